// Round 4
// baseline (108.030 us; speedup 1.0000x reference)
//
#include <hip/hip_runtime.h>
#include <hip/hip_cooperative_groups.h>
#include <math.h>

namespace cg = cooperative_groups;

#define KK 16
#define DD 16
#define NCAT 136
#define NROWS 20480
#define NTILES 320          // row tiles of 64
#define NW 8                // waves per block
#define CPW 17              // categories per wave (8*17 = 136)
#define GS 17               // padded LDS stride for g (odd -> conflict-free)
#define NCU 256             // gfx950 CUs
#define EPSF 1e-6f
#define LOG2PI_F 1.8378770664093453f
#define INV_SQRT2 0.70710678118654752f

struct SmemT {
    float  g_s[64 * GS];
    float  zz_s[64];
    float4 sC4[NCAT];   // (C, recip*sq, sq, sum mu_B^2)
    float  sK0[NCAT];   // folded per-category constant
    float  comb_m[NW * 64];
    float  comb_s[NW * 64];
};

// --- per-category constants from mu/pi (threads 0..135), incl. pi-softmax ---
__device__ __forceinline__ void phaseB_constants(
    SmemT& sm, const float* __restrict__ pi, const float* __restrict__ mu,
    int tid, int lane)
{
    if (tid >= NCAT) return;
    float pv[3];
    float lmax = -1e30f;
    #pragma unroll
    for (int j = 0; j < 3; ++j) {
        int cc = lane + j * 64;
        pv[j] = (cc < NCAT) ? pi[cc] : -1e30f;
        lmax = fmaxf(lmax, pv[j]);
    }
    #pragma unroll
    for (int off = 32; off > 0; off >>= 1)
        lmax = fmaxf(lmax, __shfl_xor(lmax, off, 64));
    float lsum = 0.f;
    #pragma unroll
    for (int j = 0; j < 3; ++j) {
        int cc = lane + j * 64;
        if (cc < NCAT) lsum += __expf(pv[j] - lmax);
    }
    #pragma unroll
    for (int off = 32; off > 0; off >>= 1)
        lsum += __shfl_xor(lsum, off, 64);

    const int c = tid;
    int a = 0, rem = c;
    while (rem >= KK - a) { rem -= KK - a; ++a; }
    const int b = a + rem;

    float inv = 0.f, Cc = 0.f, mb2 = 0.f;
    #pragma unroll
    for (int d = 0; d < DD; ++d) {
        float mb = mu[d * KK + b];
        float ma = mu[d * KK + a];
        float al = mb - ma;
        inv = fmaf(al, al, inv);
        Cc  = fmaf(al, mb, Cc);
        mb2 = fmaf(mb, mb, mb2);
    }
    float recip   = (a == b) ? 0.f : 1.f / inv;
    float clipped = fminf(fmaxf(inv, 1e-12f), 1e30f);
    float sq      = sqrtf(clipped);

    float p = __expf(pi[c] - lmax) / lsum;
    p = fminf(fmaxf(p, EPSF), 1.0f);
    float logpi = __logf(p);

    float k0;
    if (a == b) k0 = logpi - 8.f * LOG2PI_F;
    else        k0 = logpi - 8.f * LOG2PI_F + 0.5f * (LOG2PI_F - __logf(clipped));

    sm.sC4[c] = make_float4(Cc, recip * sq, sq, mb2);
    sm.sK0[c] = k0;
}

// --- one 64-row tile: returns lp for row=lane if w==0 (else 0) ---
__device__ __forceinline__ float tile_lp(
    SmemT& sm, const float* __restrict__ z, int tile, int w, int lane)
{
    const int row = tile * 64 + lane;
    const float* zr = z + row * DD;
    float zv[DD];
    #pragma unroll
    for (int i = 0; i < 4; ++i) {
        float4 v = reinterpret_cast<const float4*>(zr)[i];
        zv[4 * i + 0] = v.x; zv[4 * i + 1] = v.y;
        zv[4 * i + 2] = v.z; zv[4 * i + 3] = v.w;
    }
    // wave w computes g columns 2w, 2w+1
    {
        const float* mu2 = sm.g_s; (void)mu2;
    }
    // NOTE: mu is folded into sC4 already for constants, but g needs raw mu;
    // we stash mu columns access directly from global (L1-resident, 1 KB).
    return 0.f; // placeholder, never used (specialized below)
}

// Full tile body (needs mu for g columns). Two barriers per tile.
__device__ __forceinline__ float tile_lp_full(
    SmemT& sm, const float* __restrict__ z, const float* __restrict__ mu,
    int tile, int w, int lane)
{
    const int row = tile * 64 + lane;
    const float* zr = z + row * DD;
    float zv[DD];
    #pragma unroll
    for (int i = 0; i < 4; ++i) {
        float4 v = reinterpret_cast<const float4*>(zr)[i];
        zv[4 * i + 0] = v.x; zv[4 * i + 1] = v.y;
        zv[4 * i + 2] = v.z; zv[4 * i + 3] = v.w;
    }
    {
        const int k0 = 2 * w, k1 = 2 * w + 1;
        float g0 = 0.f, g1 = 0.f;
        #pragma unroll
        for (int d = 0; d < DD; ++d) {
            g0 = fmaf(zv[d], mu[d * KK + k0], g0);
            g1 = fmaf(zv[d], mu[d * KK + k1], g1);
        }
        sm.g_s[lane * GS + k0] = g0;
        sm.g_s[lane * GS + k1] = g1;
    }
    if (w == 0) {
        float zz = 0.f;
        #pragma unroll
        for (int d = 0; d < DD; ++d) zz = fmaf(zv[d], zv[d], zz);
        sm.zz_s[lane] = zz;
    }
    __syncthreads();   // g_s, zz_s (and, on first tile, sC4/sK0) ready

    // wave w: categories [17w, 17w+17) for row = lane; two-pass LSE
    {
        const int c0 = w * CPW;
        int a = 0, rem = c0;
        while (rem >= KK - a) { rem -= KK - a; ++a; }
        int b = a + rem;

        const float zz = sm.zz_s[lane];
        const float* grow = &sm.g_s[lane * GS];
        float val[CPW];
        float m = -1e30f;
        #pragma unroll
        for (int i = 0; i < CPW; ++i) {
            const int c = c0 + i;
            float4 k  = sm.sC4[c];               // wave-uniform broadcast
            float k0  = sm.sK0[c];
            float ga  = grow[a];
            float gb  = grow[b];
            float bsq = fmaf(-2.f, gb, zz) + k.w;
            float sab = gb - ga - k.x;
            float e2r = sab * k.y;               // = -nu*sq
            float t   = fmaf(e2r, e2r, -bsq);    // nu^2*inv - bsq
            float e1  = (k.z + e2r) * INV_SQRT2;
            float e2  = e2r * INV_SQRT2;
            float cd  = 0.5f * (erff(e1) - erff(e2));
            cd = fminf(fmaxf(cd, EPSF), 1e30f);
            float vn  = fmaf(0.5f, t, k0) + __logf(cd);
            float vd  = fmaf(-0.5f, bsq, k0);
            val[i] = (a == b) ? vd : vn;
            m = fmaxf(m, val[i]);
            if (++b == KK) { ++a; b = a; }
        }
        float ssum = 0.f;
        #pragma unroll
        for (int i = 0; i < CPW; ++i) ssum += __expf(val[i] - m);
        sm.comb_m[w * 64 + lane] = m;
        sm.comb_s[w * 64 + lane] = ssum;
    }
    __syncthreads();   // comb ready; writes of NEXT tile's comb happen after
                       // the next tile's first barrier, so wave-0 reads are safe

    float lp = 0.f;
    if (w == 0) {
        float M = sm.comb_m[lane], S = sm.comb_s[lane];
        #pragma unroll
        for (int ww = 1; ww < NW; ++ww) {
            float mm = sm.comb_m[ww * 64 + lane];
            float ss = sm.comb_s[ww * 64 + lane];
            float nm = fmaxf(M, mm);
            S = S * __expf(M - nm) + ss * __expf(mm - nm);
            M = nm;
        }
        lp = M + __logf(S);
    }
    return lp;
}

// ---------------------------------------------------------------------------
// Cooperative single-kernel path: grid-stride over 320 tiles, grid sync,
// block 0 reduces per-block partials (double, fixed order) -> out.
// ---------------------------------------------------------------------------
__global__ __launch_bounds__(512, 4) void latent_coop(
    const float* __restrict__ z,
    const float* __restrict__ pi,
    const float* __restrict__ mu,
    float* __restrict__ partials,
    float* __restrict__ out)
{
    __shared__ SmemT sm;
    const int tid  = threadIdx.x;
    const int w    = tid >> 6;
    const int lane = tid & 63;

    phaseB_constants(sm, pi, mu, tid, lane);   // covered by first tile barrier

    float acc = 0.f;
    for (int tile = blockIdx.x; tile < NTILES; tile += gridDim.x)
        acc += tile_lp_full(sm, z, mu, tile, w, lane);

    if (w == 0) {
        #pragma unroll
        for (int off = 32; off > 0; off >>= 1)
            acc += __shfl_xor(acc, off, 64);
        if (lane == 0) partials[blockIdx.x] = acc;
    }

    cg::this_grid().sync();

    if (blockIdx.x == 0 && w == 0) {
        double s = 0.0;
        for (int i = lane; i < (int)gridDim.x; i += 64)
            s += (double)partials[i];
        #pragma unroll
        for (int off = 32; off > 0; off >>= 1)
            s += __shfl_xor(s, off, 64);
        if (lane == 0) out[0] = (float)(s / (double)NROWS);
    }
}

// ---------------------------------------------------------------------------
// Fallback path (if cooperative launch unavailable): two plain kernels.
// ---------------------------------------------------------------------------
__global__ __launch_bounds__(512, 4) void latent_main_fb(
    const float* __restrict__ z,
    const float* __restrict__ pi,
    const float* __restrict__ mu,
    float* __restrict__ partials)
{
    __shared__ SmemT sm;
    const int tid  = threadIdx.x;
    const int w    = tid >> 6;
    const int lane = tid & 63;

    phaseB_constants(sm, pi, mu, tid, lane);
    float lp = tile_lp_full(sm, z, mu, blockIdx.x, w, lane);
    if (w == 0) {
        #pragma unroll
        for (int off = 32; off > 0; off >>= 1)
            lp += __shfl_xor(lp, off, 64);
        if (lane == 0) partials[blockIdx.x] = lp;
    }
}

__global__ __launch_bounds__(64) void latent_reduce_fb(
    const float* __restrict__ partials, float* __restrict__ out, int n)
{
    const int tid = threadIdx.x;
    double s = 0.0;
    for (int i = tid; i < n; i += 64) s += (double)partials[i];
    #pragma unroll
    for (int off = 32; off > 0; off >>= 1)
        s += __shfl_xor(s, off, 64);
    if (tid == 0) out[0] = (float)(s / (double)NROWS);
}

extern "C" void kernel_launch(void* const* d_in, const int* in_sizes, int n_in,
                              void* d_out, int out_size, void* d_ws, size_t ws_size,
                              hipStream_t stream) {
    const float* z  = (const float*)d_in[0];   // (2048,10,16) f32
    const float* pi = (const float*)d_in[1];   // (1,136) f32
    const float* mu = (const float*)d_in[2];   // (16,16) f32
    float* out      = (float*)d_out;           // scalar f32
    float* partials = (float*)d_ws;            // up to 320 floats

    // Co-residency-safe grid for the cooperative launch (deterministic on a
    // given device; expect 320).
    int perCU = 0;
    if (hipOccupancyMaxActiveBlocksPerMultiprocessor(&perCU, latent_coop, 512, 0)
            != hipSuccess || perCU < 1)
        perCU = 1;
    int G = perCU * NCU;
    if (G > NTILES) G = NTILES;

    void* args[] = { (void*)&z, (void*)&pi, (void*)&mu,
                     (void*)&partials, (void*)&out };
    hipError_t e = hipLaunchCooperativeKernel((const void*)latent_coop,
                                              dim3(G), dim3(512), args, 0, stream);
    if (e != hipSuccess) {
        // two-node fallback (no memset needed: partials written before read)
        latent_main_fb<<<NTILES, 512, 0, stream>>>(z, pi, mu, partials);
        latent_reduce_fb<<<1, 64, 0, stream>>>(partials, out, NTILES);
    }
}

// Round 5
// 28.000 us; speedup vs baseline: 3.8582x; 3.8582x over previous
//
#include <hip/hip_runtime.h>
#include <math.h>

#define KK 16
#define DD 16
#define NCAT 136
#define NCATP 144          // padded to 16 chunks x 9
#define NROWS 20480
#define RPB 16             // rows per block
#define NBLK (NROWS / RPB) // 1280 = 5 * 256 CUs (perfect balance)
#define CPT 9              // categories per thread
#define GS 17              // padded LDS stride for g rows
#define EPSF 1e-6f
#define LOG2PI_F 1.8378770664093453f
#define INV_SQRT2 0.70710678118654752f

// ---------------------------------------------------------------------------
// Block = 256 threads = 4 waves, owns 16 rows. Thread (r = tid>>4, ch = tid&15)
// evaluates categories [9ch, 9ch+9) (c >= 136 are pads -> -1e30) for row r.
// Row merge = 4-step shfl butterfly within the 16 lanes of the row (no LDS).
// ---------------------------------------------------------------------------
__global__ __launch_bounds__(256, 6) void latent_main(
    const float* __restrict__ z,
    const float* __restrict__ pi,
    const float* __restrict__ mu,
    float* __restrict__ partials)
{
    __shared__ float  g_s[RPB * GS];
    __shared__ float4 sC4[NCATP];   // (C, recip*sq, sq, sum mu_B^2)
    __shared__ float  sK0[NCATP];   // folded per-category constant
    __shared__ float  wsum[4];

    const int t    = threadIdx.x;
    const int wv   = t >> 6;
    const int lane = t & 63;
    const int r    = t >> 4;        // row-in-block 0..15
    const int ch   = t & 15;        // category chunk 0..15

    const int row = blockIdx.x * RPB + r;

    // --- Phase A: z row (redundant x16, L1-served), zz, g[r][ch] ---
    const float* zr = z + row * DD;
    float zv[DD];
    #pragma unroll
    for (int i = 0; i < 4; ++i) {
        float4 v = reinterpret_cast<const float4*>(zr)[i];
        zv[4*i+0] = v.x; zv[4*i+1] = v.y; zv[4*i+2] = v.z; zv[4*i+3] = v.w;
    }
    float zz = 0.f;
    #pragma unroll
    for (int d = 0; d < DD; ++d) zz = fmaf(zv[d], zv[d], zz);
    {
        float gv = 0.f;
        #pragma unroll
        for (int d = 0; d < DD; ++d) gv = fmaf(zv[d], mu[d * KK + ch], gv);
        g_s[r * GS + ch] = gv;
    }

    // --- Phase B: waves 0..2 fully active (shuffle-safe); tid<144 write ---
    if (wv < 3) {
        float pv[3];
        float lmax = -1e30f;
        #pragma unroll
        for (int j = 0; j < 3; ++j) {
            int cc = lane + j * 64;
            pv[j] = (cc < NCAT) ? pi[cc] : -1e30f;
            lmax = fmaxf(lmax, pv[j]);
        }
        #pragma unroll
        for (int off = 32; off > 0; off >>= 1)
            lmax = fmaxf(lmax, __shfl_xor(lmax, off, 64));
        float lsum = 0.f;
        #pragma unroll
        for (int j = 0; j < 3; ++j) {
            int cc = lane + j * 64;
            if (cc < NCAT) lsum += __expf(pv[j] - lmax);
        }
        #pragma unroll
        for (int off = 32; off > 0; off >>= 1)
            lsum += __shfl_xor(lsum, off, 64);

        if (t < NCATP) {
            const int c = t;
            if (c < NCAT) {
                int a = 0, rem = c;
                while (rem >= KK - a) { rem -= KK - a; ++a; }
                const int b = a + rem;

                float inv = 0.f, Cc = 0.f, mb2 = 0.f;
                #pragma unroll
                for (int d = 0; d < DD; ++d) {
                    float mb = mu[d * KK + b];
                    float ma = mu[d * KK + a];
                    float al = mb - ma;
                    inv = fmaf(al, al, inv);
                    Cc  = fmaf(al, mb, Cc);
                    mb2 = fmaf(mb, mb, mb2);
                }
                float recip   = (a == b) ? 0.f : 1.f / inv;
                float clipped = fminf(fmaxf(inv, 1e-12f), 1e30f);
                float sq      = sqrtf(clipped);

                float p = __expf(pi[c] - lmax) / lsum;
                p = fminf(fmaxf(p, EPSF), 1.0f);
                float logpi = __logf(p);

                float k0 = (a == b)
                    ? logpi - 8.f * LOG2PI_F
                    : logpi - 8.f * LOG2PI_F + 0.5f * (LOG2PI_F - __logf(clipped));

                sC4[c] = make_float4(Cc, recip * sq, sq, mb2);
                sK0[c] = k0;
            } else {                         // pads 136..143
                sC4[c] = make_float4(0.f, 0.f, 0.f, 0.f);
                sK0[c] = -1e30f;
            }
        }
    }
    __syncthreads();

    // --- Phase C: 9 categories starting at 9*ch; two-pass LSE ---
    const float* grow = &g_s[r * GS];
    int c = CPT * ch;
    int a = 0, rem = c;
    while (rem >= KK - a) { rem -= KK - a; ++a; }
    int b = a + rem;

    float val[CPT];
    float m = -1e30f;
    #pragma unroll
    for (int i = 0; i < CPT; ++i) {
        float4 k  = sC4[c];
        float k0  = sK0[c];
        float ga  = grow[a];
        float gb  = grow[b];
        float bsq = fmaf(-2.f, gb, zz) + k.w;
        float sab = gb - ga - k.x;
        float e2r = sab * k.y;               // = -nu*sq
        float tt  = fmaf(e2r, e2r, -bsq);    // nu^2*inv - bsq
        float e1  = (k.z + e2r) * INV_SQRT2;
        float e2  = e2r * INV_SQRT2;
        float cd  = 0.5f * (erff(e1) - erff(e2));
        cd = fminf(fmaxf(cd, EPSF), 1e30f);
        float vn  = fmaf(0.5f, tt, k0) + __logf(cd);
        float vd  = fmaf(-0.5f, bsq, k0);
        val[i] = (a == b) ? vd : vn;
        m = fmaxf(m, val[i]);
        if (c + 1 < NCAT) { if (++b == KK) { ++a; b = a; } }  // pads hold (15,15)
        ++c;
    }
    float s = 0.f;
    #pragma unroll
    for (int i = 0; i < CPT; ++i) s += __expf(val[i] - m);

    // --- merge (m,s) across the 16 lanes of this row (butterfly) ---
    #pragma unroll
    for (int off = 1; off < 16; off <<= 1) {
        float mo = __shfl_xor(m, off, 64);
        float so = __shfl_xor(s, off, 64);
        float nm = fmaxf(m, mo);
        s = s * __expf(m - nm) + so * __expf(mo - nm);
        m = nm;
    }
    float lp = m + __logf(s);                // identical across the 16 lanes

    // --- sum lp over this wave's 4 rows, then over 4 waves ---
    lp += __shfl_xor(lp, 16, 64);
    lp += __shfl_xor(lp, 32, 64);
    if (lane == 0) wsum[wv] = lp;
    __syncthreads();
    if (t == 0) partials[blockIdx.x] = wsum[0] + wsum[1] + wsum[2] + wsum[3];
}

// ---------------------------------------------------------------------------
// Final reduction: sum 1280 block partials (double, fixed order), /NROWS.
// ---------------------------------------------------------------------------
__global__ __launch_bounds__(256) void latent_reduce(
    const float* __restrict__ partials, float* __restrict__ out)
{
    __shared__ double dsum[4];
    const int t = threadIdx.x, wv = t >> 6, lane = t & 63;
    double s = 0.0;
    for (int i = t; i < NBLK; i += 256) s += (double)partials[i];
    #pragma unroll
    for (int off = 32; off > 0; off >>= 1)
        s += __shfl_xor(s, off, 64);
    if (lane == 0) dsum[wv] = s;
    __syncthreads();
    if (t == 0) out[0] = (float)((dsum[0] + dsum[1] + dsum[2] + dsum[3])
                                 / (double)NROWS);
}

extern "C" void kernel_launch(void* const* d_in, const int* in_sizes, int n_in,
                              void* d_out, int out_size, void* d_ws, size_t ws_size,
                              hipStream_t stream) {
    const float* z  = (const float*)d_in[0];   // (2048,10,16) f32
    const float* pi = (const float*)d_in[1];   // (1,136) f32
    const float* mu = (const float*)d_in[2];   // (16,16) f32
    float* out      = (float*)d_out;           // scalar f32
    float* partials = (float*)d_ws;            // 1280 floats

    latent_main<<<NBLK, 256, 0, stream>>>(z, pi, mu, partials);
    latent_reduce<<<1, 256, 0, stream>>>(partials, out);
}